// Round 1
// baseline (603.574 us; speedup 1.0000x reference)
//
#include <hip/hip_runtime.h>
#include <hip/hip_bf16.h>

typedef __hip_bfloat16 bf16;

// exact bf16<->f32 conversion helpers (bf16 = top 16 bits of f32, RNE round)
__device__ __forceinline__ float us2f(unsigned short u) {
  union { unsigned int ui; float f; } cv; cv.ui = ((unsigned int)u) << 16; return cv.f;
}
__device__ __forceinline__ unsigned short f2us(float f) {
  union { float f; unsigned int u; } cv; cv.f = f;
  unsigned int u = cv.u;
  return (unsigned short)((u + 0x7fffu + ((u >> 16) & 1u)) >> 16);
}
// unpack low/high bf16 of a packed dword (low ushort = even feature)
__device__ __forceinline__ float lo2f(unsigned int u) {
  union { unsigned int ui; float f; } cv; cv.ui = u << 16; return cv.f;
}
__device__ __forceinline__ float hi2f(unsigned int u) {
  union { unsigned int ui; float f; } cv; cv.ui = u & 0xffff0000u; return cv.f;
}

#define WEXP 0.36787944117144233f  // exp(-1)

// f_out[n][64] = relu(in[n][KDIM] @ W[KDIM][64] + b); in fp32 row-stride in_stride.
// fout: bf16 [n][64]. If xcopy != nullptr, copies the fp32 input rows to
// xcopy + row*320 (x pass-through; only used with KDIM=64).
// Block: 256 threads = 16 col-groups(x4 cols) x 16 row-pairs -> 32 rows/block.
template<int KDIM>
__global__ __launch_bounds__(256) void dense_relu_kernel(
    const float* __restrict__ in, int in_stride,
    const float* __restrict__ W, const float* __restrict__ b,
    bf16* __restrict__ fout, float* __restrict__ xcopy, int n)
{
  __shared__ float Ws[KDIM][68];       // pad 64->68: keeps 16B row alignment, breaks conflicts
  __shared__ float Xs[32][KDIM + 1];   // +1 pad breaks same-bank across rows
  const int tx = threadIdx.x;
  const int row0 = blockIdx.x * 32;

  // stage W (KDIM x 64 fp32), float4 vector loads
  for (int t = tx; t < KDIM * 16; t += 256) {
    float4 w4 = ((const float4*)W)[t];
    int k = t >> 4, c4 = (t & 15) * 4;
    Ws[k][c4 + 0] = w4.x; Ws[k][c4 + 1] = w4.y; Ws[k][c4 + 2] = w4.z; Ws[k][c4 + 3] = w4.w;
  }

  // stage X rows (32 x KDIM fp32)
  constexpr int CH = KDIM / 4;  // float4 chunks per row
  for (int t = tx; t < 32 * CH; t += 256) {
    int rr = t / CH, kc = t - rr * CH;
    int row = row0 + rr;
    float4 f4 = make_float4(0.f, 0.f, 0.f, 0.f);
    if (row < n)
      f4 = *(const float4*)(in + (size_t)row * in_stride + kc * 4);
    Xs[rr][kc * 4 + 0] = f4.x; Xs[rr][kc * 4 + 1] = f4.y;
    Xs[rr][kc * 4 + 2] = f4.z; Xs[rr][kc * 4 + 3] = f4.w;
    if (xcopy != nullptr && row < n)
      *(float4*)(xcopy + (size_t)row * 320 + kc * 4) = f4;
  }
  __syncthreads();

  const int c = tx & 15;        // col group: cols 4c..4c+3
  const int r = tx >> 4;        // row pair: rows 2r, 2r+1
  float acc0[4] = {0.f, 0.f, 0.f, 0.f};
  float acc1[4] = {0.f, 0.f, 0.f, 0.f};
#pragma unroll 8
  for (int k = 0; k < KDIM; ++k) {
    const float4 w4 = *(const float4*)&Ws[k][c * 4];
    const float x0 = Xs[2 * r][k];
    const float x1 = Xs[2 * r + 1][k];
    acc0[0] += x0 * w4.x; acc0[1] += x0 * w4.y; acc0[2] += x0 * w4.z; acc0[3] += x0 * w4.w;
    acc1[0] += x1 * w4.x; acc1[1] += x1 * w4.y; acc1[2] += x1 * w4.z; acc1[3] += x1 * w4.w;
  }

  const float4 bb = *(const float4*)&b[c * 4];

  int row = row0 + 2 * r;
  if (row < n) {
    ushort4 o;
    o.x = f2us(fmaxf(acc0[0] + bb.x, 0.f));
    o.y = f2us(fmaxf(acc0[1] + bb.y, 0.f));
    o.z = f2us(fmaxf(acc0[2] + bb.z, 0.f));
    o.w = f2us(fmaxf(acc0[3] + bb.w, 0.f));
    *(ushort4*)((unsigned short*)fout + (size_t)row * 64 + c * 4) = o;
  }
  row = row0 + 2 * r + 1;
  if (row < n) {
    ushort4 o;
    o.x = f2us(fmaxf(acc1[0] + bb.x, 0.f));
    o.y = f2us(fmaxf(acc1[1] + bb.y, 0.f));
    o.z = f2us(fmaxf(acc1[2] + bb.z, 0.f));
    o.w = f2us(fmaxf(acc1[3] + bb.w, 0.f));
    *(ushort4*)((unsigned short*)fout + (size_t)row * 64 + c * 4) = o;
  }
}

// KNN accumulate, wide-gather version.
// For point i: out[i*320 + j]      = WEXP*mean_k f[nk][j] - f[i][j]
//              out[i*320 + 64 + j] = WEXP*max_k  f[nk][j] - f[i][j]
// One wave per point; 4 waves/block. idx is int32.
//
// Gather restructure: a f-row is 64 bf16 = 128 B = 8 lanes x 16 B.
// Each oct (8 lanes, o = lane>>3) owns neighbors k = 4o..4o+3 (mean/max are
// order-independent, any partition works). Lane L = lane&7 holds features
// 8L..8L+7. Per k-loop iteration one global_load_dwordx4 fetches 8 neighbor
// rows for the whole wave -> 4 iterations instead of 32, 8x fewer
// lane-addresses through the coalescer. 3-round shfl_xor butterfly (8/16/32)
// combines the 8 partial streams.
__global__ __launch_bounds__(256) void accum_kernel(
    const bf16* __restrict__ f,     // [n][64] bf16
    const int* __restrict__ idx,    // [n][32] int32
    float* __restrict__ out,        // fp32, row stride 320
    int n)
{
  const int wid = threadIdx.x >> 6;
  const int lane = threadIdx.x & 63;
  const int i = blockIdx.x * 4 + wid;
  if (i >= n) return;

  int iv = 0;
  if (lane < 32) iv = idx[(size_t)i * 32 + lane];

  const int L = lane & 7;                 // feature group: features 8L..8L+7
  const int srcbase = (lane >> 3) << 2;   // oct * 4: this oct's first neighbor slot

  float s[8], m[8];
#pragma unroll
  for (int j = 0; j < 8; ++j) { s[j] = 0.f; m[j] = -3.4e38f; }

  const char* fb = (const char*)f;
#pragma unroll
  for (int t = 0; t < 4; ++t) {
    const int nk = __shfl(iv, srcbase + t);
    const unsigned off = (((unsigned)nk) << 7) + ((unsigned)L << 4);
    const uint4 d = *(const uint4*)(fb + off);
    float v;
    v = lo2f(d.x); s[0] += v; m[0] = fmaxf(m[0], v);
    v = hi2f(d.x); s[1] += v; m[1] = fmaxf(m[1], v);
    v = lo2f(d.y); s[2] += v; m[2] = fmaxf(m[2], v);
    v = hi2f(d.y); s[3] += v; m[3] = fmaxf(m[3], v);
    v = lo2f(d.z); s[4] += v; m[4] = fmaxf(m[4], v);
    v = hi2f(d.z); s[5] += v; m[5] = fmaxf(m[5], v);
    v = lo2f(d.w); s[6] += v; m[6] = fmaxf(m[6], v);
    v = hi2f(d.w); s[7] += v; m[7] = fmaxf(m[7], v);
  }

  // butterfly combine across the 8 octs (each held 4 of the 32 neighbors)
#pragma unroll
  for (int off = 8; off <= 32; off <<= 1) {
#pragma unroll
    for (int j = 0; j < 8; ++j) {
      s[j] += __shfl_xor(s[j], off);
      m[j] = fmaxf(m[j], __shfl_xor(m[j], off));
    }
  }

  // self features (same 16B slot this lane gathered)
  const uint4 sd = *(const uint4*)(fb + (((unsigned)i) << 7) + ((unsigned)L << 4));
  float self[8];
  self[0] = lo2f(sd.x); self[1] = hi2f(sd.x);
  self[2] = lo2f(sd.y); self[3] = hi2f(sd.y);
  self[4] = lo2f(sd.z); self[5] = hi2f(sd.z);
  self[6] = lo2f(sd.w); self[7] = hi2f(sd.w);

  const float cmean = WEXP / 32.0f;
  const int o = lane >> 3;
  float* orow = out + (size_t)i * 320;
  if (o == 0) {            // lanes 0..7: mean part, features 8L..8L+7 (256 B)
    float4 a, bq;
    a.x = s[0] * cmean - self[0]; a.y = s[1] * cmean - self[1];
    a.z = s[2] * cmean - self[2]; a.w = s[3] * cmean - self[3];
    bq.x = s[4] * cmean - self[4]; bq.y = s[5] * cmean - self[5];
    bq.z = s[6] * cmean - self[6]; bq.w = s[7] * cmean - self[7];
    *(float4*)(orow + 8 * L) = a;
    *(float4*)(orow + 8 * L + 4) = bq;
  } else if (o == 1) {     // lanes 8..15: max part (256 B)
    float4 a, bq;
    a.x = m[0] * WEXP - self[0]; a.y = m[1] * WEXP - self[1];
    a.z = m[2] * WEXP - self[2]; a.w = m[3] * WEXP - self[3];
    bq.x = m[4] * WEXP - self[4]; bq.y = m[5] * WEXP - self[5];
    bq.z = m[6] * WEXP - self[6]; bq.w = m[7] * WEXP - self[7];
    *(float4*)(orow + 64 + 8 * L) = a;
    *(float4*)(orow + 64 + 8 * L + 4) = bq;
  }
}

extern "C" void kernel_launch(void* const* d_in, const int* in_sizes, int n_in,
                              void* d_out, int out_size, void* d_ws, size_t ws_size,
                              hipStream_t stream) {
  const float* x  = (const float*)d_in[0];
  const int* idx  = (const int*)d_in[1];   // int64 in reference, narrowed to int32 on device
  const float* W0 = (const float*)d_in[2];
  const float* b0 = (const float*)d_in[3];
  const float* W1 = (const float*)d_in[4];
  const float* b1 = (const float*)d_in[5];
  float* out = (float*)d_out;              // fp32 [n][320]
  const int n = in_sizes[0] / 64;

  bf16* fbuf = (bf16*)d_ws;  // [n][64] bf16, reused for f0 then f1 (25.6 MB)

  const int dblocks = (n + 31) / 32;
  const int ablocks = (n + 3) / 4;

  // layer 0: f0 = relu(x@W0+b0); also copy x (fp32) into out cols 256..319
  dense_relu_kernel<64><<<dblocks, 256, 0, stream>>>(x, 64, W0, b0, fbuf, out + 256, n);
  // accumulate -> out cols 0..127 (fp32)
  accum_kernel<<<ablocks, 256, 0, stream>>>(fbuf, idx, out, n);
  // layer 1: f1 = relu(out0@W1+b1), reading out cols 0..127 (fp32, stride 320)
  dense_relu_kernel<128><<<dblocks, 256, 0, stream>>>(out, 320, W1, b1, fbuf, nullptr, n);
  // accumulate -> out cols 128..255 (fp32)
  accum_kernel<<<ablocks, 256, 0, stream>>>(fbuf, idx, out + 128, n);
}

// Round 2
// 572.339 us; speedup vs baseline: 1.0546x; 1.0546x over previous
//
#include <hip/hip_runtime.h>
#include <hip/hip_bf16.h>

typedef __hip_bfloat16 bf16;
typedef __attribute__((ext_vector_type(8))) short short8;   // 8 bf16 = 4 VGPRs (MFMA A/B frag)
typedef __attribute__((ext_vector_type(4))) float f32x4;    // MFMA C/D frag

// exact bf16<->f32 conversion helpers (bf16 = top 16 bits of f32, RNE round)
__device__ __forceinline__ float us2f(unsigned short u) {
  union { unsigned int ui; float f; } cv; cv.ui = ((unsigned int)u) << 16; return cv.f;
}
__device__ __forceinline__ unsigned short f2us(float f) {
  union { float f; unsigned int u; } cv; cv.f = f;
  unsigned int u = cv.u;
  return (unsigned short)((u + 0x7fffu + ((u >> 16) & 1u)) >> 16);
}
// unpack low/high bf16 of a packed dword (low ushort = even feature)
__device__ __forceinline__ float lo2f(unsigned int u) {
  union { unsigned int ui; float f; } cv; cv.ui = u << 16; return cv.f;
}
__device__ __forceinline__ float hi2f(unsigned int u) {
  union { unsigned int ui; float f; } cv; cv.ui = u & 0xffff0000u; return cv.f;
}

#define WEXP 0.36787944117144233f  // exp(-1)

// MFMA dense+ReLU: fout[n][64] = bf16(relu(in[n][KDIM] @ W[KDIM][64] + b)).
// in fp32, row stride in_stride. If xcopy != nullptr, copies fp32 input rows
// to xcopy + row*320 (x pass-through, KDIM=64 only).
//
// Precision: A is split hi/lo (x = bf16(x) + bf16(x - bf16(x))); two MFMAs per
// B-frag recover ~fp32 A precision. Only W's single bf16 rounding remains
// (~0.002 abs err on the dot product, below the bf16 f-storage quant step).
//
// Block: 256 thr = 4 waves; block computes 64 rows x 64 cols; wave w does rows
// 16w..16w+15 via mfma_f32_16x16x32_bf16 (4 col-tiles x KDIM/32 k-steps x 2).
template<int KDIM>
__global__ __launch_bounds__(256) void dense_mfma_kernel(
    const float* __restrict__ in, int in_stride,
    const float* __restrict__ W, const float* __restrict__ b,
    bf16* __restrict__ fout, float* __restrict__ xcopy, int n)
{
  constexpr int WT_STRIDE = KDIM + 8;  // shorts; rows 16B-aligned, 2-way-max bank pattern
  __shared__ unsigned short WT[64 * WT_STRIDE];

  const int tx = threadIdx.x;
  // stage W^T as bf16: WT[c][k] = bf16(W[k][c])
  for (int i = tx; i < KDIM * 64; i += 256) {
    int k = i >> 6, c = i & 63;
    WT[c * WT_STRIDE + k] = f2us(W[i]);
  }
  __syncthreads();

  const int wv = tx >> 6;          // wave 0..3
  const int lane = tx & 63;
  const int mrow = lane & 15;      // A-row selector / B-col selector
  const int kgrp = lane >> 4;      // k offset = 8*kgrp within 32-k step
  const int row = blockIdx.x * 64 + wv * 16 + mrow;   // A row this lane loads

  f32x4 acc[4] = {};               // 4 col-tiles (16 cols each) x 4 C-rows

#pragma unroll
  for (int ks = 0; ks < KDIM / 32; ++ks) {
    const int k0 = ks * 32 + kgrp * 8;
    float4 a0 = make_float4(0.f, 0.f, 0.f, 0.f);
    float4 a1 = make_float4(0.f, 0.f, 0.f, 0.f);
    if (row < n) {
      a0 = *(const float4*)(in + (size_t)row * in_stride + k0);
      a1 = *(const float4*)(in + (size_t)row * in_stride + k0 + 4);
    }
    if (xcopy != nullptr && row < n) {
      *(float4*)(xcopy + (size_t)row * 320 + k0) = a0;
      *(float4*)(xcopy + (size_t)row * 320 + k0 + 4) = a1;
    }
    // split fp32 -> bf16 hi + residual lo
    short8 ahi, alo;
    const float av[8] = {a0.x, a0.y, a0.z, a0.w, a1.x, a1.y, a1.z, a1.w};
#pragma unroll
    for (int j = 0; j < 8; ++j) {
      const unsigned short h = f2us(av[j]);
      ahi[j] = (short)h;
      alo[j] = (short)f2us(av[j] - us2f(h));
    }
#pragma unroll
    for (int ct = 0; ct < 4; ++ct) {
      const short8 bfr = *(const short8*)&WT[(ct * 16 + mrow) * WT_STRIDE + k0];
      acc[ct] = __builtin_amdgcn_mfma_f32_16x16x32_bf16(ahi, bfr, acc[ct], 0, 0, 0);
      acc[ct] = __builtin_amdgcn_mfma_f32_16x16x32_bf16(alo, bfr, acc[ct], 0, 0, 0);
    }
  }

  // epilogue: bias + relu + bf16 store. C layout: col=lane&15, row=4*kgrp+r.
#pragma unroll
  for (int ct = 0; ct < 4; ++ct) {
    const int col = ct * 16 + mrow;
    const float bc = b[col];
#pragma unroll
    for (int r = 0; r < 4; ++r) {
      const int orow = blockIdx.x * 64 + wv * 16 + kgrp * 4 + r;
      if (orow < n) {
        const float v = fmaxf(acc[ct][r] + bc, 0.f);
        ((unsigned short*)fout)[(size_t)orow * 64 + col] = f2us(v);
      }
    }
  }
}

// KNN accumulate, wide-gather version (perf-equal to narrow; memory-wall bound).
// For point i: out[i*320 + j]      = WEXP*mean_k f[nk][j] - f[i][j]
//              out[i*320 + 64 + j] = WEXP*max_k  f[nk][j] - f[i][j]
// One wave per point; 4 waves/block. idx is int32.
__global__ __launch_bounds__(256) void accum_kernel(
    const bf16* __restrict__ f,     // [n][64] bf16
    const int* __restrict__ idx,    // [n][32] int32
    float* __restrict__ out,        // fp32, row stride 320
    int n)
{
  const int wid = threadIdx.x >> 6;
  const int lane = threadIdx.x & 63;
  const int i = blockIdx.x * 4 + wid;
  if (i >= n) return;

  int iv = 0;
  if (lane < 32) iv = idx[(size_t)i * 32 + lane];

  const int L = lane & 7;                 // feature group: features 8L..8L+7
  const int srcbase = (lane >> 3) << 2;   // oct * 4: this oct's first neighbor slot

  float s[8], m[8];
#pragma unroll
  for (int j = 0; j < 8; ++j) { s[j] = 0.f; m[j] = -3.4e38f; }

  const char* fb = (const char*)f;
#pragma unroll
  for (int t = 0; t < 4; ++t) {
    const int nk = __shfl(iv, srcbase + t);
    const unsigned off = (((unsigned)nk) << 7) + ((unsigned)L << 4);
    const uint4 d = *(const uint4*)(fb + off);
    float v;
    v = lo2f(d.x); s[0] += v; m[0] = fmaxf(m[0], v);
    v = hi2f(d.x); s[1] += v; m[1] = fmaxf(m[1], v);
    v = lo2f(d.y); s[2] += v; m[2] = fmaxf(m[2], v);
    v = hi2f(d.y); s[3] += v; m[3] = fmaxf(m[3], v);
    v = lo2f(d.z); s[4] += v; m[4] = fmaxf(m[4], v);
    v = hi2f(d.z); s[5] += v; m[5] = fmaxf(m[5], v);
    v = lo2f(d.w); s[6] += v; m[6] = fmaxf(m[6], v);
    v = hi2f(d.w); s[7] += v; m[7] = fmaxf(m[7], v);
  }

  // butterfly combine across the 8 octs (each held 4 of the 32 neighbors)
#pragma unroll
  for (int off = 8; off <= 32; off <<= 1) {
#pragma unroll
    for (int j = 0; j < 8; ++j) {
      s[j] += __shfl_xor(s[j], off);
      m[j] = fmaxf(m[j], __shfl_xor(m[j], off));
    }
  }

  // self features (same 16B slot this lane gathered)
  const uint4 sd = *(const uint4*)(fb + (((unsigned)i) << 7) + ((unsigned)L << 4));
  float self[8];
  self[0] = lo2f(sd.x); self[1] = hi2f(sd.x);
  self[2] = lo2f(sd.y); self[3] = hi2f(sd.y);
  self[4] = lo2f(sd.z); self[5] = hi2f(sd.z);
  self[6] = lo2f(sd.w); self[7] = hi2f(sd.w);

  const float cmean = WEXP / 32.0f;
  const int o = lane >> 3;
  float* orow = out + (size_t)i * 320;
  if (o == 0) {            // lanes 0..7: mean part, features 8L..8L+7 (256 B)
    float4 a, bq;
    a.x = s[0] * cmean - self[0]; a.y = s[1] * cmean - self[1];
    a.z = s[2] * cmean - self[2]; a.w = s[3] * cmean - self[3];
    bq.x = s[4] * cmean - self[4]; bq.y = s[5] * cmean - self[5];
    bq.z = s[6] * cmean - self[6]; bq.w = s[7] * cmean - self[7];
    *(float4*)(orow + 8 * L) = a;
    *(float4*)(orow + 8 * L + 4) = bq;
  } else if (o == 1) {     // lanes 8..15: max part (256 B)
    float4 a, bq;
    a.x = m[0] * WEXP - self[0]; a.y = m[1] * WEXP - self[1];
    a.z = m[2] * WEXP - self[2]; a.w = m[3] * WEXP - self[3];
    bq.x = m[4] * WEXP - self[4]; bq.y = m[5] * WEXP - self[5];
    bq.z = m[6] * WEXP - self[6]; bq.w = m[7] * WEXP - self[7];
    *(float4*)(orow + 64 + 8 * L) = a;
    *(float4*)(orow + 64 + 8 * L + 4) = bq;
  }
}

extern "C" void kernel_launch(void* const* d_in, const int* in_sizes, int n_in,
                              void* d_out, int out_size, void* d_ws, size_t ws_size,
                              hipStream_t stream) {
  const float* x  = (const float*)d_in[0];
  const int* idx  = (const int*)d_in[1];   // int64 in reference, narrowed to int32 on device
  const float* W0 = (const float*)d_in[2];
  const float* b0 = (const float*)d_in[3];
  const float* W1 = (const float*)d_in[4];
  const float* b1 = (const float*)d_in[5];
  float* out = (float*)d_out;              // fp32 [n][320]
  const int n = in_sizes[0] / 64;

  bf16* fbuf = (bf16*)d_ws;  // [n][64] bf16, reused for f0 then f1 (25.6 MB)

  const int dblocks = (n + 63) / 64;
  const int ablocks = (n + 3) / 4;

  // layer 0: f0 = relu(x@W0+b0) via MFMA; also copy x (fp32) into out cols 256..319
  dense_mfma_kernel<64><<<dblocks, 256, 0, stream>>>(x, 64, W0, b0, fbuf, out + 256, n);
  // accumulate -> out cols 0..127 (fp32)
  accum_kernel<<<ablocks, 256, 0, stream>>>(fbuf, idx, out, n);
  // layer 1: f1 = relu(out0@W1+b1) via MFMA, reading out cols 0..127 (fp32, stride 320)
  dense_mfma_kernel<128><<<dblocks, 256, 0, stream>>>(out, 320, W1, b1, fbuf, nullptr, n);
  // accumulate -> out cols 128..255 (fp32)
  accum_kernel<<<ablocks, 256, 0, stream>>>(fbuf, idx, out + 128, n);
}

// Round 4
// 558.520 us; speedup vs baseline: 1.0807x; 1.0247x over previous
//
#include <hip/hip_runtime.h>
#include <hip/hip_bf16.h>

typedef __hip_bfloat16 bf16;
typedef __attribute__((ext_vector_type(8))) short short8;   // 8 bf16 = 4 VGPRs (MFMA A/B frag)
typedef __attribute__((ext_vector_type(4))) float f32x4;    // MFMA C/D frag

// exact bf16<->f32 conversion helpers (bf16 = top 16 bits of f32, RNE round)
__device__ __forceinline__ float us2f(unsigned short u) {
  union { unsigned int ui; float f; } cv; cv.ui = ((unsigned int)u) << 16; return cv.f;
}
__device__ __forceinline__ unsigned short f2us(float f) {
  union { float f; unsigned int u; } cv; cv.f = f;
  unsigned int u = cv.u;
  return (unsigned short)((u + 0x7fffu + ((u >> 16) & 1u)) >> 16);
}
// unpack low/high bf16 of a packed dword (low ushort = even feature)
__device__ __forceinline__ float lo2f(unsigned int u) {
  union { unsigned int ui; float f; } cv; cv.ui = u << 16; return cv.f;
}
__device__ __forceinline__ float hi2f(unsigned int u) {
  union { unsigned int ui; float f; } cv; cv.ui = u & 0xffff0000u; return cv.f;
}

#define WEXP 0.36787944117144233f  // exp(-1)

// MFMA dense+ReLU: fout[n][64] = bf16(relu(in[n][KDIM] @ W[KDIM][64] + b)).
// in fp32, row stride in_stride. If xcopy != nullptr, copies fp32 input rows
// to xcopy + row*320 (x pass-through, KDIM=64 only).
//
// Operand-swapped MFMA: D = Wfrag * xfrag, so D-row = out-feature and each
// lane owns 4 CONSECUTIVE out columns of one point -> ushort4 stores.
// W is staged in LDS pre-arranged in exact A-frag order (16B/lane,
// lane-consecutive) -> conflict-free ds_read_b128, no address math.
//
// Precision: x is split hi/lo (x = bf16(x) + bf16(x - bf16(x))); two MFMAs per
// W-frag recover ~fp32 x precision; only W's single bf16 rounding remains.
//
// Block: 256 thr = 4 waves; block does 64 points x 64 cols; wave w does points
// 16w..16w+15 (n = 200000 divides evenly into 64-point blocks: 3125 blocks).
template<int KDIM>
__global__ __launch_bounds__(256) void dense_mfma_kernel(
    const float* __restrict__ in, int in_stride,
    const float* __restrict__ W, const float* __restrict__ b,
    bf16* __restrict__ fout, float* __restrict__ xcopy, int n)
{
  constexpr int NKS = KDIM / 32;            // 32-k steps
  constexpr int NFRAG = NKS * 4 * 64;       // frag granules of 8 shorts (per ks x ct x lane)
  __shared__ unsigned short WTf[NFRAG * 8]; // 8 KB (K=64) / 16 KB (K=128), no pad needed

  const int tx = threadIdx.x;
  // stage W frags: fi = (ks*4+ct)*64 + lane; element j of lane's frag is
  //   bf16(W[ks*32 + (lane>>4)*8 + j][ct*16 + (lane&15)])
#pragma unroll
  for (int fch = 0; fch < NFRAG / 256; ++fch) {
    const int fi = fch * 256 + tx;
    const int ln = fi & 63;
    const int ct = (fi >> 6) & 3;
    const int ks = fi >> 8;
    const int c  = ct * 16 + (ln & 15);
    const int kb = ks * 32 + (ln >> 4) * 8;
    short8 wf;
#pragma unroll
    for (int j = 0; j < 8; ++j)
      wf[j] = (short)f2us(W[(size_t)(kb + j) * 64 + c]);
    *(short8*)&WTf[(size_t)fi * 8] = wf;
  }
  __syncthreads();

  const int wv = tx >> 6;          // wave 0..3
  const int lane = tx & 63;
  const int mrow = lane & 15;      // point-within-tile (B col) selector
  const int kgrp = lane >> 4;      // k sub-offset; also D-row group
  const int row = blockIdx.x * 64 + wv * 16 + mrow;   // this lane's point

  f32x4 acc[4] = {};               // ct = out-feature tile (16 cols each)

#pragma unroll
  for (int ks = 0; ks < NKS; ++ks) {
    const int k0 = ks * 32 + kgrp * 8;
    float4 a0 = make_float4(0.f, 0.f, 0.f, 0.f);
    float4 a1 = make_float4(0.f, 0.f, 0.f, 0.f);
    if (row < n) {
      a0 = *(const float4*)(in + (size_t)row * in_stride + k0);
      a1 = *(const float4*)(in + (size_t)row * in_stride + k0 + 4);
    }
    if (xcopy != nullptr && row < n) {
      *(float4*)(xcopy + (size_t)row * 320 + k0) = a0;
      *(float4*)(xcopy + (size_t)row * 320 + k0 + 4) = a1;
    }
    // split fp32 -> bf16 hi + residual lo
    short8 xhi, xlo;
    const float av[8] = {a0.x, a0.y, a0.z, a0.w, a1.x, a1.y, a1.z, a1.w};
#pragma unroll
    for (int j = 0; j < 8; ++j) {
      const unsigned short h = f2us(av[j]);
      xhi[j] = (short)h;
      xlo[j] = (short)f2us(av[j] - us2f(h));
    }
#pragma unroll
    for (int ct = 0; ct < 4; ++ct) {
      const short8 wfr = *(const short8*)&WTf[(size_t)((ks * 4 + ct) * 64 + lane) * 8];
      acc[ct] = __builtin_amdgcn_mfma_f32_16x16x32_bf16(wfr, xhi, acc[ct], 0, 0, 0);
      acc[ct] = __builtin_amdgcn_mfma_f32_16x16x32_bf16(wfr, xlo, acc[ct], 0, 0, 0);
    }
  }

  // epilogue: D[m=4*kgrp+r][nn=mrow] = outfeat ct*16+4*kgrp+r of point `row`.
  if (row < n) {
    unsigned short* fr = (unsigned short*)fout + (size_t)row * 64;
#pragma unroll
    for (int ct = 0; ct < 4; ++ct) {
      const int c0 = ct * 16 + kgrp * 4;
      const float4 bb = *(const float4*)&b[c0];
      ushort4 o;
      o.x = f2us(fmaxf(acc[ct][0] + bb.x, 0.f));
      o.y = f2us(fmaxf(acc[ct][1] + bb.y, 0.f));
      o.z = f2us(fmaxf(acc[ct][2] + bb.z, 0.f));
      o.w = f2us(fmaxf(acc[ct][3] + bb.w, 0.f));
      *(ushort4*)&fr[c0] = o;
    }
  }
}

// KNN accumulate, wide-gather + explicit load batching.
// For point i: out[i*320 + j]      = WEXP*mean_k f[nk][j] - f[i][j]
//              out[i*320 + 64 + j] = WEXP*max_k  f[nk][j] - f[i][j]
// One wave per point; 4 waves/block. idx is int32.
// Each oct (8 lanes) owns 4 neighbors; lane L=lane&7 holds features 8L..8L+7;
// all 5 gathers (4 neighbor chunks + self) issued before any reduction.
__global__ __launch_bounds__(256) void accum_kernel(
    const bf16* __restrict__ f,     // [n][64] bf16
    const int* __restrict__ idx,    // [n][32] int32
    float* __restrict__ out,        // fp32, row stride 320
    int n)
{
  const int wid = threadIdx.x >> 6;
  const int lane = threadIdx.x & 63;
  const int i = blockIdx.x * 4 + wid;
  if (i >= n) return;

  int iv = 0;
  if (lane < 32) iv = idx[(size_t)i * 32 + lane];

  const int L = lane & 7;                 // feature group: features 8L..8L+7
  const int srcbase = (lane >> 3) << 2;   // oct * 4: this oct's first neighbor slot
  const char* fb = (const char*)f;

  // self row: independent, issue first
  const uint4 sd = *(const uint4*)(fb + (((unsigned)i) << 7) + ((unsigned)L << 4));

  int nk[4];
#pragma unroll
  for (int t = 0; t < 4; ++t) nk[t] = __shfl(iv, srcbase + t);

  uint4 d[4];
#pragma unroll
  for (int t = 0; t < 4; ++t)
    d[t] = *(const uint4*)(fb + (((unsigned)nk[t]) << 7) + ((unsigned)L << 4));

  float s[8], m[8];
#pragma unroll
  for (int j = 0; j < 8; ++j) { s[j] = 0.f; m[j] = -3.4e38f; }
#pragma unroll
  for (int t = 0; t < 4; ++t) {
    float v;
    v = lo2f(d[t].x); s[0] += v; m[0] = fmaxf(m[0], v);
    v = hi2f(d[t].x); s[1] += v; m[1] = fmaxf(m[1], v);
    v = lo2f(d[t].y); s[2] += v; m[2] = fmaxf(m[2], v);
    v = hi2f(d[t].y); s[3] += v; m[3] = fmaxf(m[3], v);
    v = lo2f(d[t].z); s[4] += v; m[4] = fmaxf(m[4], v);
    v = hi2f(d[t].z); s[5] += v; m[5] = fmaxf(m[5], v);
    v = lo2f(d[t].w); s[6] += v; m[6] = fmaxf(m[6], v);
    v = hi2f(d[t].w); s[7] += v; m[7] = fmaxf(m[7], v);
  }

  // butterfly combine across the 8 octs (each held 4 of the 32 neighbors)
#pragma unroll
  for (int off = 8; off <= 32; off <<= 1) {
#pragma unroll
    for (int j = 0; j < 8; ++j) {
      s[j] += __shfl_xor(s[j], off);
      m[j] = fmaxf(m[j], __shfl_xor(m[j], off));
    }
  }

  float self[8];
  self[0] = lo2f(sd.x); self[1] = hi2f(sd.x);
  self[2] = lo2f(sd.y); self[3] = hi2f(sd.y);
  self[4] = lo2f(sd.z); self[5] = hi2f(sd.z);
  self[6] = lo2f(sd.w); self[7] = hi2f(sd.w);

  const float cmean = WEXP / 32.0f;
  const int o = lane >> 3;
  float* orow = out + (size_t)i * 320;
  if (o == 0) {            // lanes 0..7: mean part, features 8L..8L+7 (256 B)
    float4 a, bq;
    a.x = s[0] * cmean - self[0]; a.y = s[1] * cmean - self[1];
    a.z = s[2] * cmean - self[2]; a.w = s[3] * cmean - self[3];
    bq.x = s[4] * cmean - self[4]; bq.y = s[5] * cmean - self[5];
    bq.z = s[6] * cmean - self[6]; bq.w = s[7] * cmean - self[7];
    *(float4*)(orow + 8 * L) = a;
    *(float4*)(orow + 8 * L + 4) = bq;
  } else if (o == 1) {     // lanes 8..15: max part (256 B)
    float4 a, bq;
    a.x = m[0] * WEXP - self[0]; a.y = m[1] * WEXP - self[1];
    a.z = m[2] * WEXP - self[2]; a.w = m[3] * WEXP - self[3];
    bq.x = m[4] * WEXP - self[4]; bq.y = m[5] * WEXP - self[5];
    bq.z = m[6] * WEXP - self[6]; bq.w = m[7] * WEXP - self[7];
    *(float4*)(orow + 64 + 8 * L) = a;
    *(float4*)(orow + 64 + 8 * L + 4) = bq;
  }
}

extern "C" void kernel_launch(void* const* d_in, const int* in_sizes, int n_in,
                              void* d_out, int out_size, void* d_ws, size_t ws_size,
                              hipStream_t stream) {
  const float* x  = (const float*)d_in[0];
  const int* idx  = (const int*)d_in[1];   // int64 in reference, narrowed to int32 on device
  const float* W0 = (const float*)d_in[2];
  const float* b0 = (const float*)d_in[3];
  const float* W1 = (const float*)d_in[4];
  const float* b1 = (const float*)d_in[5];
  float* out = (float*)d_out;              // fp32 [n][320]
  const int n = in_sizes[0] / 64;

  bf16* fbuf = (bf16*)d_ws;  // [n][64] bf16, reused for f0 then f1 (25.6 MB)

  const int dblocks = (n + 63) / 64;
  const int ablocks = (n + 3) / 4;

  // layer 0: f0 = relu(x@W0+b0) via MFMA; also copy x (fp32) into out cols 256..319
  dense_mfma_kernel<64><<<dblocks, 256, 0, stream>>>(x, 64, W0, b0, fbuf, out + 256, n);
  // accumulate -> out cols 0..127 (fp32)
  accum_kernel<<<ablocks, 256, 0, stream>>>(fbuf, idx, out, n);
  // layer 1: f1 = relu(out0@W1+b1) via MFMA, reading out cols 0..127 (fp32, stride 320)
  dense_mfma_kernel<128><<<dblocks, 256, 0, stream>>>(out, 320, W1, b1, fbuf, nullptr, n);
  // accumulate -> out cols 128..255 (fp32)
  accum_kernel<<<ablocks, 256, 0, stream>>>(fbuf, idx, out + 128, n);
}